// Round 2
// baseline (1608.616 us; speedup 1.0000x reference)
//
#include <hip/hip_runtime.h>
#include <hip/hip_bf16.h>
#include <stdint.h>
#include <stddef.h>

#define NN 100000
#define NE 300000
#define FINDIM 128
#define HD 256
#define NG 4000
#define NLAYER 5

typedef __attribute__((ext_vector_type(8))) short bf8;
typedef __attribute__((ext_vector_type(4))) float f4;

__device__ __forceinline__ unsigned short f2bf(float f){
  union { float f; unsigned u; } uf; uf.f = f;
  unsigned r = uf.u + 0x7fffu + ((uf.u >> 16) & 1u);
  return (unsigned short)(r >> 16);
}
__device__ __forceinline__ float bf2f(unsigned short h){
  union { unsigned u; float f; } uf; uf.u = ((unsigned)h) << 16; return uf.f;
}

// ---------------- zero fill ----------------
__global__ void k_zero(int* __restrict__ p, int n){
  int i = blockIdx.x*256 + threadIdx.x;
  if(i < n) p[i] = 0;
}

// ---------------- CSR build ----------------
__global__ void k_count(const int* __restrict__ ei, int* __restrict__ counts){
  int e = blockIdx.x*256 + threadIdx.x;
  if(e < NE) atomicAdd(&counts[ei[NE + e]], 1);
}

__global__ void k_scan_partial(const int* __restrict__ counts, int* __restrict__ partials){
  __shared__ int sw[4];
  int b = blockIdx.x, t = threadIdx.x;
  int base = b*1024 + t*4;
  int s = 0;
  #pragma unroll
  for(int j=0;j<4;j++){ int i = base+j; if(i < NN) s += counts[i]; }
  #pragma unroll
  for(int d=1; d<64; d<<=1) s += __shfl_xor(s, d, 64);
  if((t & 63) == 0) sw[t>>6] = s;
  __syncthreads();
  if(t == 0) partials[b] = sw[0]+sw[1]+sw[2]+sw[3];
}

__global__ void k_scan_tot(int* __restrict__ partials, int* __restrict__ offsets, int nb){
  __shared__ int sm[128];
  int t = threadIdx.x;
  int v = (t < nb) ? partials[t] : 0;
  sm[t] = v; __syncthreads();
  for(int d=1; d<128; d<<=1){
    int x = 0;
    if(t >= d) x = sm[t-d];
    __syncthreads();
    sm[t] += x;
    __syncthreads();
  }
  if(t < nb) partials[t] = sm[t] - v;   // exclusive
  if(t == 127) offsets[NN] = sm[127];   // total == NE
}

__global__ void k_scan_final(const int* __restrict__ counts, const int* __restrict__ partials,
                             int* __restrict__ offsets, int* __restrict__ cursor){
  __shared__ int wsum[4];
  int b = blockIdx.x, t = threadIdx.x;
  int base = b*1024 + t*4;
  int c[4]; int ts = 0;
  #pragma unroll
  for(int j=0;j<4;j++){ int i = base+j; c[j] = (i < NN) ? counts[i] : 0; ts += c[j]; }
  int lane = t & 63;
  int inc = ts;
  #pragma unroll
  for(int d=1; d<64; d<<=1){ int x = __shfl_up(inc, d, 64); if(lane >= d) inc += x; }
  if(lane == 63) wsum[t>>6] = inc;
  __syncthreads();
  int woff = 0;
  for(int w2=0; w2<(t>>6); w2++) woff += wsum[w2];
  int excl = partials[b] + woff + inc - ts;
  #pragma unroll
  for(int j=0;j<4;j++){
    int i = base+j;
    if(i < NN){ offsets[i] = excl; cursor[i] = excl; excl += c[j]; }
  }
}

__global__ void k_fill(const int* __restrict__ ei, int* __restrict__ cursor, int* __restrict__ eidx){
  int e = blockIdx.x*256 + threadIdx.x;
  if(e < NE){
    int d = ei[NE + e];
    int pos = atomicAdd(&cursor[d], 1);
    eidx[pos] = ei[e];
  }
}

// ---------------- weight transpose/convert: src f32 [K,Ncols] -> dst bf16 [Ncols,K] ----------------
__global__ void k_wt(const float* __restrict__ src, unsigned short* __restrict__ dst, int K, int Ncols){
  int l = blockIdx.y;
  size_t base = (size_t)l * K * Ncols;
  int i = blockIdx.x*256 + threadIdx.x;
  if(i < K*Ncols){
    int k = i / Ncols, n = i % Ncols;
    dst[base + (size_t)n*K + k] = f2bf(src[base + i]);
  }
}

// ---------------- GEMM: C[M,256](bf16) = act(A)[M,K] @ Bt^T + bias ----------------
// Bt bf16 [256 n][K k]. PRE: a -> max(preS[k]*a+preT[k],0) in staging. AF32: A is f32 else bf16.
template<int K, int PRE, bool RELUOUT, bool STATS, bool AF32>
__global__ __launch_bounds__(256, 2) void k_gemm(
    const void* __restrict__ A, const unsigned short* __restrict__ Bt,
    const float* __restrict__ bias, const float* __restrict__ preS,
    const float* __restrict__ preT, unsigned short* __restrict__ C,
    float* __restrict__ stats)
{
  __shared__ unsigned short As[128*40];
  __shared__ unsigned short Bs[128*40];
  const int m0 = blockIdx.x*128, n0 = blockIdx.y*128;
  const int t = threadIdx.x;
  const int lane = t & 63, w = t >> 6;
  const int q = lane >> 4, ln = lane & 15;
  const int wm = w & 1, wn = w >> 1;

  f4 acc[4][4];
  #pragma unroll
  for(int i=0;i<4;i++)
    #pragma unroll
    for(int j=0;j<4;j++) acc[i][j] = (f4){0.f,0.f,0.f,0.f};

  for(int kk=0; kk<K; kk+=32){
    if(AF32){
      const float* Af = (const float*)A;
      #pragma unroll
      for(int i=0;i<4;i++){
        int idx = t + 256*i;
        int r = idx >> 3;
        int c4 = (idx & 7) << 2;
        int gm = m0 + r;
        f4 v = (f4){0.f,0.f,0.f,0.f};
        if(gm < NN) v = *(const f4*)(Af + (size_t)gm*K + kk + c4);
        ushort4 u;
        u.x = f2bf(v.x); u.y = f2bf(v.y); u.z = f2bf(v.z); u.w = f2bf(v.w);
        *(ushort4*)&As[r*40 + c4] = u;
      }
    } else {
      const unsigned short* Ah = (const unsigned short*)A;
      #pragma unroll
      for(int i=0;i<2;i++){
        int idx = t + 256*i;
        int r = idx >> 2;
        int c8 = (idx & 3) << 3;
        int gm = m0 + r;
        uint4 u = {0u,0u,0u,0u};
        if(gm < NN) u = *(const uint4*)(Ah + (size_t)gm*K + kk + c8);
        if(PRE == 1){
          f4 s0 = *(const f4*)(preS + kk + c8);
          f4 s1 = *(const f4*)(preS + kk + c8 + 4);
          f4 t0 = *(const f4*)(preT + kk + c8);
          f4 t1 = *(const f4*)(preT + kk + c8 + 4);
          float sv[8] = {s0.x,s0.y,s0.z,s0.w,s1.x,s1.y,s1.z,s1.w};
          float tv[8] = {t0.x,t0.y,t0.z,t0.w,t1.x,t1.y,t1.z,t1.w};
          unsigned short* us = (unsigned short*)&u;
          #pragma unroll
          for(int j=0;j<8;j++){
            float v = bf2f(us[j]);
            v = fmaxf(fmaf(sv[j], v, tv[j]), 0.f);
            us[j] = f2bf(v);
          }
        }
        *(uint4*)&As[r*40 + c8] = u;
      }
    }
    #pragma unroll
    for(int i=0;i<2;i++){
      int idx = t + 256*i;
      int r = idx >> 2;
      int c8 = (idx & 3) << 3;
      uint4 u = *(const uint4*)(Bt + (size_t)(n0 + r)*K + kk + c8);
      *(uint4*)&Bs[r*40 + c8] = u;
    }
    __syncthreads();
    bf8 af[4], bb[4];
    #pragma unroll
    for(int mi=0;mi<4;mi++) af[mi] = *(const bf8*)&As[(wm*64 + mi*16 + ln)*40 + q*8];
    #pragma unroll
    for(int ni=0;ni<4;ni++) bb[ni] = *(const bf8*)&Bs[(wn*64 + ni*16 + ln)*40 + q*8];
    #pragma unroll
    for(int mi=0;mi<4;mi++)
      #pragma unroll
      for(int ni=0;ni<4;ni++)
        acc[mi][ni] = __builtin_amdgcn_mfma_f32_16x16x32_bf16(af[mi], bb[ni], acc[mi][ni], 0, 0, 0);
    __syncthreads();
  }

  #pragma unroll
  for(int ni=0;ni<4;ni++){
    int gn = n0 + wn*64 + ni*16 + ln;
    float b = bias[gn];
    float s = 0.f, ss = 0.f;
    #pragma unroll
    for(int mi=0;mi<4;mi++){
      int gmb = m0 + wm*64 + mi*16 + q*4;
      #pragma unroll
      for(int r=0;r<4;r++){
        int gm = gmb + r;
        if(gm < NN){
          float v = acc[mi][ni][r] + b;
          if(RELUOUT) v = fmaxf(v, 0.f);
          C[(size_t)gm*HD + gn] = f2bf(v);
          if(STATS){ s += v; ss = fmaf(v, v, ss); }
        }
      }
    }
    if(STATS){
      s  += __shfl_xor(s, 16, 64);  s  += __shfl_xor(s, 32, 64);
      ss += __shfl_xor(ss, 16, 64); ss += __shfl_xor(ss, 32, 64);
      if(q == 0){
        atomicAdd(&stats[gn], s);
        atomicAdd(&stats[HD + gn], ss);
      }
    }
  }
}

// ---------------- BN finalize ----------------
__global__ void k_bnfin(const float* __restrict__ cs, const float* __restrict__ g,
                        const float* __restrict__ be, float* __restrict__ sc, float* __restrict__ sh){
  int c = threadIdx.x;
  float mean = cs[c] * (1.0f/NN);
  float var  = cs[HD + c] * (1.0f/NN) - mean*mean;
  float s = g[c] * rsqrtf(var + 1e-5f);
  sc[c] = s;
  sh[c] = be[c] - mean*s;
}

// ---------------- aggregation: dst[n] = (1+eps)*act(src[n]) + sum_{in-edges} act(src[src_e]) ----------------
__global__ __launch_bounds__(256) void k_agg(const unsigned short* __restrict__ src,
    unsigned short* __restrict__ dst,
    const int* __restrict__ offs, const int* __restrict__ eidx,
    const float* __restrict__ eps, int l,
    const float* __restrict__ sc, const float* __restrict__ sh, int ident)
{
  int wv = threadIdx.x >> 6;
  int n = blockIdx.x*4 + wv;
  if(n >= NN) return;
  int lane = threadIdx.x & 63;
  int c = lane << 2;
  f4 s4 = (f4){0.f,0.f,0.f,0.f}, t4 = (f4){0.f,0.f,0.f,0.f};
  if(!ident){ s4 = *(const f4*)(sc + c); t4 = *(const f4*)(sh + c); }
  float ep = 1.f + eps[l];
  ushort4 hv = *(const ushort4*)(src + (size_t)n*HD + c);
  f4 a;
  a.x = bf2f(hv.x); a.y = bf2f(hv.y); a.z = bf2f(hv.z); a.w = bf2f(hv.w);
  if(!ident){
    a.x = fmaxf(fmaf(s4.x, a.x, t4.x), 0.f);
    a.y = fmaxf(fmaf(s4.y, a.y, t4.y), 0.f);
    a.z = fmaxf(fmaf(s4.z, a.z, t4.z), 0.f);
    a.w = fmaxf(fmaf(s4.w, a.w, t4.w), 0.f);
  }
  f4 acc;
  acc.x = ep*a.x; acc.y = ep*a.y; acc.z = ep*a.z; acc.w = ep*a.w;
  int lo = offs[n], hi = offs[n+1];
  for(int e=lo; e<hi; e++){
    int sidx = eidx[e];
    ushort4 uv = *(const ushort4*)(src + (size_t)sidx*HD + c);
    f4 u;
    u.x = bf2f(uv.x); u.y = bf2f(uv.y); u.z = bf2f(uv.z); u.w = bf2f(uv.w);
    if(!ident){
      u.x = fmaxf(fmaf(s4.x, u.x, t4.x), 0.f);
      u.y = fmaxf(fmaf(s4.y, u.y, t4.y), 0.f);
      u.z = fmaxf(fmaf(s4.z, u.z, t4.z), 0.f);
      u.w = fmaxf(fmaf(s4.w, u.w, t4.w), 0.f);
    }
    acc.x += u.x; acc.y += u.y; acc.z += u.z; acc.w += u.w;
  }
  ushort4 o;
  o.x = f2bf(acc.x); o.y = f2bf(acc.y); o.z = f2bf(acc.z); o.w = f2bf(acc.w);
  *(ushort4*)(dst + (size_t)n*HD + c) = o;
}

// ---------------- pooling ----------------
__device__ __forceinline__ int lowb(const int* __restrict__ arr, int n, int key){
  int lo = 0, hi = n;
  while(lo < hi){ int mid = (lo + hi) >> 1; if(arr[mid] < key) lo = mid + 1; else hi = mid; }
  return lo;
}

__global__ __launch_bounds__(256) void k_pool(const unsigned short* __restrict__ src,
    const int* __restrict__ batch,
    const float* __restrict__ sc, const float* __restrict__ sh, float* __restrict__ pooled)
{
  int wv = threadIdx.x >> 6;
  int g = blockIdx.x*4 + wv;
  if(g >= NG) return;
  int lane = threadIdx.x & 63;
  int c = lane << 2;
  int lo = lowb(batch, NN, g);
  int hi = lowb(batch, NN, g+1);
  f4 s4 = *(const f4*)(sc + c);
  f4 t4 = *(const f4*)(sh + c);
  f4 acc = (f4){0.f,0.f,0.f,0.f};
  for(int n=lo; n<hi; n++){
    ushort4 uv = *(const ushort4*)(src + (size_t)n*HD + c);
    acc.x += fmaxf(fmaf(s4.x, bf2f(uv.x), t4.x), 0.f);
    acc.y += fmaxf(fmaf(s4.y, bf2f(uv.y), t4.y), 0.f);
    acc.z += fmaxf(fmaf(s4.z, bf2f(uv.z), t4.z), 0.f);
    acc.w += fmaxf(fmaf(s4.w, bf2f(uv.w), t4.w), 0.f);
  }
  float inv = 1.0f / fmaxf((float)(hi - lo), 1.0f);
  acc.x *= inv; acc.y *= inv; acc.z *= inv; acc.w *= inv;
  *(f4*)(pooled + (size_t)g*HD + c) = acc;
}

// ---------------- head ----------------
__global__ __launch_bounds__(128) void k_head(const float* __restrict__ pooled,
    const float* __restrict__ W1, const float* __restrict__ b1,
    const float* __restrict__ W2, const float* __restrict__ b2, float* __restrict__ out)
{
  __shared__ float p[HD];
  __shared__ float red[2];
  int g = blockIdx.x, t = threadIdx.x;
  if(t < 64) *(f4*)&p[t*4] = *(const f4*)(pooled + (size_t)g*HD + t*4);
  __syncthreads();
  float s = b1[t];
  for(int k=0;k<HD;k++) s = fmaf(p[k], W1[k*128 + t], s);
  float o = fmaxf(s, 0.f) * W2[t];
  #pragma unroll
  for(int d=1; d<64; d<<=1) o += __shfl_xor(o, d, 64);
  if((t & 63) == 0) red[t>>6] = o;
  __syncthreads();
  if(t == 0) out[g] = red[0] + red[1] + b2[0];
}

// ---------------- launch ----------------
extern "C" void kernel_launch(void* const* d_in, const int* in_sizes, int n_in,
                              void* d_out, int out_size, void* d_ws, size_t ws_size,
                              hipStream_t stream) {
  const float* x    = (const float*)d_in[0];
  const int*   ei   = (const int*)  d_in[1];
  const int*   bat  = (const int*)  d_in[2];
  const float* inW  = (const float*)d_in[3];
  const float* inb  = (const float*)d_in[4];
  const float* W1   = (const float*)d_in[5];
  const float* b1   = (const float*)d_in[6];
  const float* g1   = (const float*)d_in[7];
  const float* be1  = (const float*)d_in[8];
  const float* W2   = (const float*)d_in[9];
  const float* b2   = (const float*)d_in[10];
  const float* g2   = (const float*)d_in[11];
  const float* be2  = (const float*)d_in[12];
  const float* eps  = (const float*)d_in[13];
  const float* hW1  = (const float*)d_in[14];
  const float* hb1  = (const float*)d_in[15];
  const float* hW2  = (const float*)d_in[16];
  const float* hb2  = (const float*)d_in[17];
  float* out = (float*)d_out;

  char* p = (char*)d_ws;
  auto alloc = [&](size_t bytes)->char*{
    char* r = p; p += (bytes + 255) & ~(size_t)255; return r;
  };
  unsigned short* B0 = (unsigned short*)alloc((size_t)NN*HD*2);  // 51.2 MB
  unsigned short* B1 = (unsigned short*)alloc((size_t)NN*HD*2);  // 51.2 MB
  unsigned short* Wtin = (unsigned short*)alloc((size_t)FINDIM*HD*2);
  unsigned short* Wt1  = (unsigned short*)alloc((size_t)NLAYER*HD*HD*2);
  unsigned short* Wt2  = (unsigned short*)alloc((size_t)NLAYER*HD*HD*2);
  int* counts  = (int*)alloc((size_t)NN*4);
  int* offsets = (int*)alloc((size_t)(NN+1)*4);
  int* cursor  = (int*)alloc((size_t)NN*4);
  int* eidx    = (int*)alloc((size_t)NE*4);
  int* partials= (int*)alloc(128*4);
  float* cs    = (float*)alloc(4*HD*4);
  float* bnp   = (float*)alloc(4*HD*4);
  float* pooled= (float*)alloc((size_t)NG*HD*4);
  // total ≈ 110.5 MB

  // CSR build (once per call, reused by all layers)
  k_zero<<<(NN+255)/256, 256, 0, stream>>>(counts, NN);
  k_count<<<(NE+255)/256, 256, 0, stream>>>(ei, counts);
  int nb = (NN + 1023)/1024;
  k_scan_partial<<<nb, 256, 0, stream>>>(counts, partials);
  k_scan_tot<<<1, 128, 0, stream>>>(partials, offsets, nb);
  k_scan_final<<<nb, 256, 0, stream>>>(counts, partials, offsets, cursor);
  k_fill<<<(NE+255)/256, 256, 0, stream>>>(ei, cursor, eidx);

  // weights -> bf16 [n][k]
  k_wt<<<dim3((FINDIM*HD+255)/256, 1), 256, 0, stream>>>(inW, Wtin, FINDIM, HD);
  k_wt<<<dim3((HD*HD+255)/256, NLAYER), 256, 0, stream>>>(W1, Wt1, HD, HD);
  k_wt<<<dim3((HD*HD+255)/256, NLAYER), 256, 0, stream>>>(W2, Wt2, HD, HD);

  dim3 gg((NN+127)/128, 2);
  // input projection: B0 = relu(x @ inW + inb)
  k_gemm<FINDIM, 0, true, false, true><<<gg, 256, 0, stream>>>(x, Wtin, inb, nullptr, nullptr, B0, nullptr);

  float* sc1 = bnp, *sh1 = bnp + HD, *sc2 = bnp + 2*HD, *sh2 = bnp + 3*HD;
  unsigned short* hbuf = B0;
  unsigned short* tbuf = B1;
  for(int l=0; l<NLAYER; l++){
    k_zero<<<4, 256, 0, stream>>>((int*)cs, 4*HD);
    // tbuf = (1+eps)*act(hbuf) + gather-sum(act(hbuf))   (act = identity for l==0)
    k_agg<<<(NN+3)/4, 256, 0, stream>>>(hbuf, tbuf, offsets, eidx, eps, l, sc2, sh2, l==0 ? 1 : 0);
    // hbuf = tbuf @ W1 + b1 (pre-BN), colstats -> cs[0:2H]
    k_gemm<HD, 0, false, true, false><<<gg, 256, 0, stream>>>(tbuf, Wt1 + (size_t)l*HD*HD, b1 + l*HD,
                                                              nullptr, nullptr, hbuf, cs);
    k_bnfin<<<1, HD, 0, stream>>>(cs, g1 + l*HD, be1 + l*HD, sc1, sh1);
    // tbuf = act1(hbuf) @ W2 + b2 (pre-BN), colstats -> cs[2H:4H]
    k_gemm<HD, 1, false, true, false><<<gg, 256, 0, stream>>>(hbuf, Wt2 + (size_t)l*HD*HD, b2 + l*HD,
                                                              sc1, sh1, tbuf, cs + 2*HD);
    k_bnfin<<<1, HD, 0, stream>>>(cs + 2*HD, g2 + l*HD, be2 + l*HD, sc2, sh2);
    // swap: tbuf now holds layer output (pre-BN repr with sc2/sh2)
    unsigned short* tmp = hbuf; hbuf = tbuf; tbuf = tmp;
  }

  k_pool<<<(NG+3)/4, 256, 0, stream>>>(hbuf, bat, sc2, sh2, pooled);
  k_head<<<NG, 128, 0, stream>>>(pooled, hW1, hb1, hW2, hb2, out);
}

// Round 3
// 1025.694 us; speedup vs baseline: 1.5683x; 1.5683x over previous
//
#include <hip/hip_runtime.h>
#include <hip/hip_bf16.h>
#include <stdint.h>
#include <stddef.h>

#define NN 100000
#define NE 300000
#define FINDIM 128
#define HD 256
#define NG 4000
#define NLAYER 5
#define MPAD 100032   // 1563*64, padded row count for activation buffers

typedef __attribute__((ext_vector_type(8))) short bf8;
typedef __attribute__((ext_vector_type(4))) float f4;

__device__ __forceinline__ unsigned short f2bf(float f){
  union { float f; unsigned u; } uf; uf.f = f;
  unsigned r = uf.u + 0x7fffu + ((uf.u >> 16) & 1u);
  return (unsigned short)(r >> 16);
}
__device__ __forceinline__ float bf2f(unsigned short h){
  union { unsigned u; float f; } uf; uf.u = ((unsigned)h) << 16; return uf.f;
}

__device__ __forceinline__ void gload16(const void* g, void* l){
  __builtin_amdgcn_global_load_lds((const __attribute__((address_space(1))) void*)g,
                                   (__attribute__((address_space(3))) void*)l, 16, 0, 0);
}

// ---------------- zero fill ----------------
__global__ void k_zero(int* __restrict__ p, int n){
  int i = blockIdx.x*256 + threadIdx.x;
  if(i < n) p[i] = 0;
}

// ---------------- CSR build ----------------
__global__ void k_count(const int* __restrict__ ei, int* __restrict__ counts){
  int e = blockIdx.x*256 + threadIdx.x;
  if(e < NE) atomicAdd(&counts[ei[NE + e]], 1);
}

__global__ void k_scan_partial(const int* __restrict__ counts, int* __restrict__ partials){
  __shared__ int sw[4];
  int b = blockIdx.x, t = threadIdx.x;
  int base = b*1024 + t*4;
  int s = 0;
  #pragma unroll
  for(int j=0;j<4;j++){ int i = base+j; if(i < NN) s += counts[i]; }
  #pragma unroll
  for(int d=1; d<64; d<<=1) s += __shfl_xor(s, d, 64);
  if((t & 63) == 0) sw[t>>6] = s;
  __syncthreads();
  if(t == 0) partials[b] = sw[0]+sw[1]+sw[2]+sw[3];
}

__global__ void k_scan_tot(int* __restrict__ partials, int* __restrict__ offsets, int nb){
  __shared__ int sm[128];
  int t = threadIdx.x;
  int v = (t < nb) ? partials[t] : 0;
  sm[t] = v; __syncthreads();
  for(int d=1; d<128; d<<=1){
    int x = 0;
    if(t >= d) x = sm[t-d];
    __syncthreads();
    sm[t] += x;
    __syncthreads();
  }
  if(t < nb) partials[t] = sm[t] - v;   // exclusive
  if(t == 127) offsets[NN] = sm[127];   // total == NE
}

__global__ void k_scan_final(const int* __restrict__ counts, const int* __restrict__ partials,
                             int* __restrict__ offsets, int* __restrict__ cursor){
  __shared__ int wsum[4];
  int b = blockIdx.x, t = threadIdx.x;
  int base = b*1024 + t*4;
  int c[4]; int ts = 0;
  #pragma unroll
  for(int j=0;j<4;j++){ int i = base+j; c[j] = (i < NN) ? counts[i] : 0; ts += c[j]; }
  int lane = t & 63;
  int inc = ts;
  #pragma unroll
  for(int d=1; d<64; d<<=1){ int x = __shfl_up(inc, d, 64); if(lane >= d) inc += x; }
  if(lane == 63) wsum[t>>6] = inc;
  __syncthreads();
  int woff = 0;
  for(int w2=0; w2<(t>>6); w2++) woff += wsum[w2];
  int excl = partials[b] + woff + inc - ts;
  #pragma unroll
  for(int j=0;j<4;j++){
    int i = base+j;
    if(i < NN){ offsets[i] = excl; cursor[i] = excl; excl += c[j]; }
  }
}

__global__ void k_fill(const int* __restrict__ ei, int* __restrict__ cursor, int* __restrict__ eidx){
  int e = blockIdx.x*256 + threadIdx.x;
  if(e < NE){
    int d = ei[NE + e];
    int pos = atomicAdd(&cursor[d], 1);
    eidx[pos] = ei[e];
  }
}

// ---------------- weight transpose/convert: src f32 [K,Ncols] -> dst bf16 [Ncols,K] ----------------
__global__ void k_wt(const float* __restrict__ src, unsigned short* __restrict__ dst, int K, int Ncols){
  int l = blockIdx.y;
  size_t base = (size_t)l * K * Ncols;
  int i = blockIdx.x*256 + threadIdx.x;
  if(i < K*Ncols){
    int k = i / Ncols, n = i % Ncols;
    dst[base + (size_t)n*K + k] = f2bf(src[base + i]);
  }
}

// ---------------- GEMM: C[M,256](bf16) = act(A)[M,K] @ Bt^T + bias ----------------
// Block = 64m x 256n, 4 waves of 64x64. K-slab = 32.
// STAGE: 0 = A bf16 via global_load_lds; 1 = A bf16 + BN/ReLU pre-transform (manual stage);
//        2 = A f32 (manual stage, bounds-guarded).
// XOR swizzle: 16B chunk stored at LDS position p holds global chunk c = p ^ ((row>>1)&3)
// -> linear per-lane DMA layout, 2-way (free) banked ds_read_b128 frag loads.
template<int K, int STAGE, bool RELUOUT, bool STATS>
__global__ __launch_bounds__(256, 2) void k_gemm(
    const void* __restrict__ A, const unsigned short* __restrict__ Bt,
    const float* __restrict__ bias, const float* __restrict__ preS,
    const float* __restrict__ preT, unsigned short* __restrict__ C,
    float* __restrict__ stats)
{
  __shared__ __align__(16) unsigned short As[64*32];     //  4 KB
  __shared__ __align__(16) unsigned short Bs[256*32];    // 16 KB
  __shared__ __align__(16) unsigned short Cs[4*16*72];   //  9 KB epilogue scratch
  const int m0 = blockIdx.x*64;
  const int t = threadIdx.x;
  const int lane = t & 63, w = t >> 6;
  const int q = lane >> 4, ln = lane & 15;
  const int hs = (ln >> 1) & 3;          // read-side swizzle key
  const int srow = lane >> 2;            // DMA: row within 16-row segment
  const int cc   = (lane & 3) ^ ((lane >> 3) & 3);  // DMA: swizzled global chunk
  const int mr = t >> 2;                 // manual stage: row 0..63
  const int mc = (t & 3) ^ ((t >> 3) & 3);          // manual stage: global chunk

  f4 acc[4][4];
  #pragma unroll
  for(int i=0;i<4;i++)
    #pragma unroll
    for(int j=0;j<4;j++) acc[i][j] = (f4){0.f,0.f,0.f,0.f};

  for(int kk=0; kk<K; kk+=32){
    if(STAGE == 0){
      const unsigned short* Ah = (const unsigned short*)A;
      gload16(&Ah[(size_t)(m0 + w*16 + srow)*K + kk + cc*8], &As[w*512]);
    } else if(STAGE == 1){
      const unsigned short* Ah = (const unsigned short*)A;
      uint4 u = *(const uint4*)&Ah[(size_t)(m0 + mr)*K + kk + mc*8];
      int kb = kk + mc*8;
      unsigned short* us = (unsigned short*)&u;
      #pragma unroll
      for(int j=0;j<8;j++){
        float v = bf2f(us[j]);
        v = fmaxf(fmaf(preS[kb+j], v, preT[kb+j]), 0.f);
        us[j] = f2bf(v);
      }
      *(uint4*)&As[t*8] = u;   // linear: conflict-free
    } else {
      const float* Af = (const float*)A;
      int gm = m0 + mr;
      f4 v0 = (f4){0.f,0.f,0.f,0.f}, v1 = (f4){0.f,0.f,0.f,0.f};
      if(gm < NN){
        v0 = *(const f4*)&Af[(size_t)gm*K + kk + mc*8];
        v1 = *(const f4*)&Af[(size_t)gm*K + kk + mc*8 + 4];
      }
      ushort4 a0, a1;
      a0.x = f2bf(v0.x); a0.y = f2bf(v0.y); a0.z = f2bf(v0.z); a0.w = f2bf(v0.w);
      a1.x = f2bf(v1.x); a1.y = f2bf(v1.y); a1.z = f2bf(v1.z); a1.w = f2bf(v1.w);
      *(ushort4*)&As[t*8]     = a0;
      *(ushort4*)&As[t*8 + 4] = a1;
    }
    // B staging: always async DMA (no transform ever needed on B)
    #pragma unroll
    for(int j=0;j<4;j++)
      gload16(&Bt[(size_t)(w*64 + j*16 + srow)*K + kk + cc*8], &Bs[w*2048 + j*512]);
    __syncthreads();

    bf8 af[4], bb[4];
    #pragma unroll
    for(int mi=0;mi<4;mi++) af[mi] = *(const bf8*)&As[(mi*16 + ln)*32 + (q ^ hs)*8];
    #pragma unroll
    for(int ni=0;ni<4;ni++) bb[ni] = *(const bf8*)&Bs[(w*64 + ni*16 + ln)*32 + (q ^ hs)*8];
    #pragma unroll
    for(int mi=0;mi<4;mi++)
      #pragma unroll
      for(int ni=0;ni<4;ni++)
        acc[mi][ni] = __builtin_amdgcn_mfma_f32_16x16x32_bf16(af[mi], bb[ni], acc[mi][ni], 0, 0, 0);
    __syncthreads();
  }

  // ---- stats (pre-BN column sum / sumsq over valid rows) ----
  if(STATS){
    #pragma unroll
    for(int ni=0;ni<4;ni++){
      int gn = w*64 + ni*16 + ln;
      float b = bias[gn];
      float s = 0.f, ss = 0.f;
      #pragma unroll
      for(int mi=0;mi<4;mi++){
        #pragma unroll
        for(int r=0;r<4;r++){
          int gm = m0 + mi*16 + q*4 + r;
          if(gm < NN){
            float v = acc[mi][ni][r] + b;
            s += v; ss = fmaf(v, v, ss);
          }
        }
      }
      s  += __shfl_xor(s, 16, 64);  s  += __shfl_xor(s, 32, 64);
      ss += __shfl_xor(ss, 16, 64); ss += __shfl_xor(ss, 32, 64);
      if(q == 0){
        atomicAdd(&stats[gn], s);
        atomicAdd(&stats[HD + gn], ss);
      }
    }
  }

  // ---- coalesced store via per-wave LDS scratch ----
  unsigned short* wsc = &Cs[w*1152];   // 16 rows x 72 (stride keeps b128 16B-aligned)
  #pragma unroll
  for(int mi=0;mi<4;mi++){
    #pragma unroll
    for(int ni=0;ni<4;ni++){
      float b = bias[w*64 + ni*16 + ln];
      #pragma unroll
      for(int r=0;r<4;r++){
        float v = acc[mi][ni][r] + b;
        if(RELUOUT) v = fmaxf(v, 0.f);
        wsc[(q*4 + r)*72 + ni*16 + ln] = f2bf(v);
      }
    }
    int lrow = lane >> 2;
    int gm = m0 + mi*16 + lrow;
    int ch = lane & 3;
    if(gm < NN){
      uint4 u0 = *(const uint4*)&wsc[lrow*72 + ch*8];
      uint4 u1 = *(const uint4*)&wsc[lrow*72 + (ch+4)*8];
      *(uint4*)&C[(size_t)gm*HD + w*64 + ch*8]     = u0;
      *(uint4*)&C[(size_t)gm*HD + w*64 + (ch+4)*8] = u1;
    }
  }
}

// ---------------- BN finalize ----------------
__global__ void k_bnfin(const float* __restrict__ cs, const float* __restrict__ g,
                        const float* __restrict__ be, float* __restrict__ sc, float* __restrict__ sh){
  int c = threadIdx.x;
  float mean = cs[c] * (1.0f/NN);
  float var  = cs[HD + c] * (1.0f/NN) - mean*mean;
  float s = g[c] * rsqrtf(var + 1e-5f);
  sc[c] = s;
  sh[c] = be[c] - mean*s;
}

// ---------------- aggregation: dst[n] = (1+eps)*act(src[n]) + sum_{in-edges} act(src[src_e]) ----------------
__device__ __forceinline__ f4 act4(ushort4 uv, f4 s4, f4 t4, int ident){
  f4 u;
  u.x = bf2f(uv.x); u.y = bf2f(uv.y); u.z = bf2f(uv.z); u.w = bf2f(uv.w);
  if(!ident){
    u.x = fmaxf(fmaf(s4.x, u.x, t4.x), 0.f);
    u.y = fmaxf(fmaf(s4.y, u.y, t4.y), 0.f);
    u.z = fmaxf(fmaf(s4.z, u.z, t4.z), 0.f);
    u.w = fmaxf(fmaf(s4.w, u.w, t4.w), 0.f);
  }
  return u;
}

__global__ __launch_bounds__(256) void k_agg(const unsigned short* __restrict__ src,
    unsigned short* __restrict__ dst,
    const int* __restrict__ offs, const int* __restrict__ eidx,
    const float* __restrict__ eps, int l,
    const float* __restrict__ sc, const float* __restrict__ sh, int ident)
{
  int wv = threadIdx.x >> 6;
  int n = blockIdx.x*4 + wv;
  if(n >= NN) return;
  int lane = threadIdx.x & 63;
  int c = lane << 2;
  f4 s4 = (f4){0.f,0.f,0.f,0.f}, t4 = (f4){0.f,0.f,0.f,0.f};
  if(!ident){ s4 = *(const f4*)(sc + c); t4 = *(const f4*)(sh + c); }
  float ep = 1.f + eps[l];
  f4 a = act4(*(const ushort4*)(src + (size_t)n*HD + c), s4, t4, ident);
  f4 acc;
  acc.x = ep*a.x; acc.y = ep*a.y; acc.z = ep*a.z; acc.w = ep*a.w;
  int lo = offs[n], hi = offs[n+1];
  for(int base = lo; base < hi; base += 64){
    int rem = hi - base; if(rem > 64) rem = 64;
    int idx = 0;
    if(base + lane < hi) idx = eidx[base + lane];
    int j = 0;
    for(; j + 4 <= rem; j += 4){
      int s0 = __shfl(idx, j, 64),   s1 = __shfl(idx, j+1, 64);
      int s2 = __shfl(idx, j+2, 64), s3 = __shfl(idx, j+3, 64);
      ushort4 u0 = *(const ushort4*)(src + (size_t)s0*HD + c);
      ushort4 u1 = *(const ushort4*)(src + (size_t)s1*HD + c);
      ushort4 u2 = *(const ushort4*)(src + (size_t)s2*HD + c);
      ushort4 u3 = *(const ushort4*)(src + (size_t)s3*HD + c);
      f4 a0 = act4(u0, s4, t4, ident), a1 = act4(u1, s4, t4, ident);
      f4 a2 = act4(u2, s4, t4, ident), a3 = act4(u3, s4, t4, ident);
      acc.x += (a0.x + a1.x) + (a2.x + a3.x);
      acc.y += (a0.y + a1.y) + (a2.y + a3.y);
      acc.z += (a0.z + a1.z) + (a2.z + a3.z);
      acc.w += (a0.w + a1.w) + (a2.w + a3.w);
    }
    for(; j < rem; j++){
      int s0 = __shfl(idx, j, 64);
      f4 a0 = act4(*(const ushort4*)(src + (size_t)s0*HD + c), s4, t4, ident);
      acc.x += a0.x; acc.y += a0.y; acc.z += a0.z; acc.w += a0.w;
    }
  }
  ushort4 o;
  o.x = f2bf(acc.x); o.y = f2bf(acc.y); o.z = f2bf(acc.z); o.w = f2bf(acc.w);
  *(ushort4*)(dst + (size_t)n*HD + c) = o;
}

// ---------------- pooling ----------------
__device__ __forceinline__ int lowb(const int* __restrict__ arr, int n, int key){
  int lo = 0, hi = n;
  while(lo < hi){ int mid = (lo + hi) >> 1; if(arr[mid] < key) lo = mid + 1; else hi = mid; }
  return lo;
}

__global__ __launch_bounds__(256) void k_pool(const unsigned short* __restrict__ src,
    const int* __restrict__ batch,
    const float* __restrict__ sc, const float* __restrict__ sh, float* __restrict__ pooled)
{
  int wv = threadIdx.x >> 6;
  int g = blockIdx.x*4 + wv;
  if(g >= NG) return;
  int lane = threadIdx.x & 63;
  int c = lane << 2;
  int lo = lowb(batch, NN, g);
  int hi = lowb(batch, NN, g+1);
  f4 s4 = *(const f4*)(sc + c);
  f4 t4 = *(const f4*)(sh + c);
  f4 acc = (f4){0.f,0.f,0.f,0.f};
  for(int n=lo; n<hi; n++){
    ushort4 uv = *(const ushort4*)(src + (size_t)n*HD + c);
    acc.x += fmaxf(fmaf(s4.x, bf2f(uv.x), t4.x), 0.f);
    acc.y += fmaxf(fmaf(s4.y, bf2f(uv.y), t4.y), 0.f);
    acc.z += fmaxf(fmaf(s4.z, bf2f(uv.z), t4.z), 0.f);
    acc.w += fmaxf(fmaf(s4.w, bf2f(uv.w), t4.w), 0.f);
  }
  float inv = 1.0f / fmaxf((float)(hi - lo), 1.0f);
  acc.x *= inv; acc.y *= inv; acc.z *= inv; acc.w *= inv;
  *(f4*)(pooled + (size_t)g*HD + c) = acc;
}

// ---------------- head ----------------
__global__ __launch_bounds__(128) void k_head(const float* __restrict__ pooled,
    const float* __restrict__ W1, const float* __restrict__ b1,
    const float* __restrict__ W2, const float* __restrict__ b2, float* __restrict__ out)
{
  __shared__ float p[HD];
  __shared__ float red[2];
  int g = blockIdx.x, t = threadIdx.x;
  if(t < 64) *(f4*)&p[t*4] = *(const f4*)(pooled + (size_t)g*HD + t*4);
  __syncthreads();
  float s = b1[t];
  for(int k=0;k<HD;k++) s = fmaf(p[k], W1[k*128 + t], s);
  float o = fmaxf(s, 0.f) * W2[t];
  #pragma unroll
  for(int d=1; d<64; d<<=1) o += __shfl_xor(o, d, 64);
  if((t & 63) == 0) red[t>>6] = o;
  __syncthreads();
  if(t == 0) out[g] = red[0] + red[1] + b2[0];
}

// ---------------- launch ----------------
extern "C" void kernel_launch(void* const* d_in, const int* in_sizes, int n_in,
                              void* d_out, int out_size, void* d_ws, size_t ws_size,
                              hipStream_t stream) {
  const float* x    = (const float*)d_in[0];
  const int*   ei   = (const int*)  d_in[1];
  const int*   bat  = (const int*)  d_in[2];
  const float* inW  = (const float*)d_in[3];
  const float* inb  = (const float*)d_in[4];
  const float* W1   = (const float*)d_in[5];
  const float* b1   = (const float*)d_in[6];
  const float* g1   = (const float*)d_in[7];
  const float* be1  = (const float*)d_in[8];
  const float* W2   = (const float*)d_in[9];
  const float* b2   = (const float*)d_in[10];
  const float* g2   = (const float*)d_in[11];
  const float* be2  = (const float*)d_in[12];
  const float* eps  = (const float*)d_in[13];
  const float* hW1  = (const float*)d_in[14];
  const float* hb1  = (const float*)d_in[15];
  const float* hW2  = (const float*)d_in[16];
  const float* hb2  = (const float*)d_in[17];
  float* out = (float*)d_out;

  char* p = (char*)d_ws;
  auto alloc = [&](size_t bytes)->char*{
    char* r = p; p += (bytes + 255) & ~(size_t)255; return r;
  };
  unsigned short* B0 = (unsigned short*)alloc((size_t)MPAD*HD*2);  // 51.2 MB (padded)
  unsigned short* B1 = (unsigned short*)alloc((size_t)MPAD*HD*2);  // 51.2 MB (padded)
  unsigned short* Wtin = (unsigned short*)alloc((size_t)FINDIM*HD*2);
  unsigned short* Wt1  = (unsigned short*)alloc((size_t)NLAYER*HD*HD*2);
  unsigned short* Wt2  = (unsigned short*)alloc((size_t)NLAYER*HD*HD*2);
  int* counts  = (int*)alloc((size_t)NN*4);
  int* offsets = (int*)alloc((size_t)(NN+1)*4);
  int* cursor  = (int*)alloc((size_t)NN*4);
  int* eidx    = (int*)alloc((size_t)NE*4);
  int* partials= (int*)alloc(128*4);
  float* cs    = (float*)alloc(4*HD*4);
  float* bnp   = (float*)alloc(4*HD*4);
  float* pooled= (float*)alloc((size_t)NG*HD*4);

  // CSR build (once per call, reused by all layers)
  k_zero<<<(NN+255)/256, 256, 0, stream>>>(counts, NN);
  k_count<<<(NE+255)/256, 256, 0, stream>>>(ei, counts);
  int nb = (NN + 1023)/1024;
  k_scan_partial<<<nb, 256, 0, stream>>>(counts, partials);
  k_scan_tot<<<1, 128, 0, stream>>>(partials, offsets, nb);
  k_scan_final<<<nb, 256, 0, stream>>>(counts, partials, offsets, cursor);
  k_fill<<<(NE+255)/256, 256, 0, stream>>>(ei, cursor, eidx);

  // weights -> bf16 [n][k]
  k_wt<<<dim3((FINDIM*HD+255)/256, 1), 256, 0, stream>>>(inW, Wtin, FINDIM, HD);
  k_wt<<<dim3((HD*HD+255)/256, NLAYER), 256, 0, stream>>>(W1, Wt1, HD, HD);
  k_wt<<<dim3((HD*HD+255)/256, NLAYER), 256, 0, stream>>>(W2, Wt2, HD, HD);

  const int MB = MPAD/64;  // 1563 m-blocks
  // input projection: B0 = relu(x @ inW + inb)
  k_gemm<FINDIM, 2, true, false><<<MB, 256, 0, stream>>>(x, Wtin, inb, nullptr, nullptr, B0, nullptr);

  float* sc1 = bnp, *sh1 = bnp + HD, *sc2 = bnp + 2*HD, *sh2 = bnp + 3*HD;
  unsigned short* hbuf = B0;
  unsigned short* tbuf = B1;
  for(int l=0; l<NLAYER; l++){
    k_zero<<<4, 256, 0, stream>>>((int*)cs, 4*HD);
    // tbuf = (1+eps)*act(hbuf) + gather-sum(act(hbuf))   (act = identity for l==0)
    k_agg<<<(NN+3)/4, 256, 0, stream>>>(hbuf, tbuf, offsets, eidx, eps, l, sc2, sh2, l==0 ? 1 : 0);
    // hbuf = tbuf @ W1 + b1 (pre-BN), colstats -> cs[0:2H]
    k_gemm<HD, 0, false, true><<<MB, 256, 0, stream>>>(tbuf, Wt1 + (size_t)l*HD*HD, b1 + l*HD,
                                                       nullptr, nullptr, hbuf, cs);
    k_bnfin<<<1, HD, 0, stream>>>(cs, g1 + l*HD, be1 + l*HD, sc1, sh1);
    // tbuf = act1(hbuf) @ W2 + b2 (pre-BN), colstats -> cs[2H:4H]
    k_gemm<HD, 1, false, true><<<MB, 256, 0, stream>>>(hbuf, Wt2 + (size_t)l*HD*HD, b2 + l*HD,
                                                       sc1, sh1, tbuf, cs + 2*HD);
    k_bnfin<<<1, HD, 0, stream>>>(cs + 2*HD, g2 + l*HD, be2 + l*HD, sc2, sh2);
    unsigned short* tmp = hbuf; hbuf = tbuf; tbuf = tmp;
  }

  k_pool<<<(NG+3)/4, 256, 0, stream>>>(hbuf, bat, sc2, sh2, pooled);
  k_head<<<NG, 128, 0, stream>>>(pooled, hW1, hb1, hW2, hb2, out);
}

// Round 4
// 1022.745 us; speedup vs baseline: 1.5728x; 1.0029x over previous
//
#include <hip/hip_runtime.h>
#include <hip/hip_bf16.h>
#include <stdint.h>
#include <stddef.h>

#define NN 100000
#define NE 300000
#define FINDIM 128
#define HD 256
#define NG 4000
#define NLAYER 5
#define MPAD 100032   // 1563*64

typedef __attribute__((ext_vector_type(8))) short bf8;
typedef __attribute__((ext_vector_type(4))) float f4;

#define FENCE() __asm__ volatile("" ::: "memory")
#define WAITVM5() __asm__ volatile("s_waitcnt vmcnt(5)" ::: "memory")
#define WAITVM0() __asm__ volatile("s_waitcnt vmcnt(0)" ::: "memory")
#define WAITVM5L0() __asm__ volatile("s_waitcnt vmcnt(5) lgkmcnt(0)" ::: "memory")
#define WAITLGKM() __asm__ volatile("s_waitcnt lgkmcnt(0)" ::: "memory")
#define BARRIER() do { FENCE(); __builtin_amdgcn_s_barrier(); FENCE(); } while(0)

__device__ __forceinline__ unsigned short f2bf(float f){
  union { float f; unsigned u; } uf; uf.f = f;
  unsigned r = uf.u + 0x7fffu + ((uf.u >> 16) & 1u);
  return (unsigned short)(r >> 16);
}
__device__ __forceinline__ float bf2f(unsigned short h){
  union { unsigned u; float f; } uf; uf.u = ((unsigned)h) << 16; return uf.f;
}

__device__ __forceinline__ void gload16(const void* g, void* l){
  __builtin_amdgcn_global_load_lds((const __attribute__((address_space(1))) void*)g,
                                   (__attribute__((address_space(3))) void*)l, 16, 0, 0);
}

// ---------------- zero fill ----------------
__global__ void k_zero(int* __restrict__ p, int n){
  int i = blockIdx.x*256 + threadIdx.x;
  if(i < n) p[i] = 0;
}

// ---------------- CSR build ----------------
__global__ void k_count(const int* __restrict__ ei, int* __restrict__ counts){
  int e = blockIdx.x*256 + threadIdx.x;
  if(e < NE) atomicAdd(&counts[ei[NE + e]], 1);
}

__global__ void k_scan_partial(const int* __restrict__ counts, int* __restrict__ partials){
  __shared__ int sw[4];
  int b = blockIdx.x, t = threadIdx.x;
  int base = b*1024 + t*4;
  int s = 0;
  #pragma unroll
  for(int j=0;j<4;j++){ int i = base+j; if(i < NN) s += counts[i]; }
  #pragma unroll
  for(int d=1; d<64; d<<=1) s += __shfl_xor(s, d, 64);
  if((t & 63) == 0) sw[t>>6] = s;
  __syncthreads();
  if(t == 0) partials[b] = sw[0]+sw[1]+sw[2]+sw[3];
}

__global__ void k_scan_tot(int* __restrict__ partials, int* __restrict__ offsets, int nb){
  __shared__ int sm[128];
  int t = threadIdx.x;
  int v = (t < nb) ? partials[t] : 0;
  sm[t] = v; __syncthreads();
  for(int d=1; d<128; d<<=1){
    int x = 0;
    if(t >= d) x = sm[t-d];
    __syncthreads();
    sm[t] += x;
    __syncthreads();
  }
  if(t < nb) partials[t] = sm[t] - v;   // exclusive
  if(t == 127) offsets[NN] = sm[127];   // total == NE
}

__global__ void k_scan_final(const int* __restrict__ counts, const int* __restrict__ partials,
                             int* __restrict__ offsets, int* __restrict__ cursor){
  __shared__ int wsum[4];
  int b = blockIdx.x, t = threadIdx.x;
  int base = b*1024 + t*4;
  int c[4]; int ts = 0;
  #pragma unroll
  for(int j=0;j<4;j++){ int i = base+j; c[j] = (i < NN) ? counts[i] : 0; ts += c[j]; }
  int lane = t & 63;
  int inc = ts;
  #pragma unroll
  for(int d=1; d<64; d<<=1){ int x = __shfl_up(inc, d, 64); if(lane >= d) inc += x; }
  if(lane == 63) wsum[t>>6] = inc;
  __syncthreads();
  int woff = 0;
  for(int w2=0; w2<(t>>6); w2++) woff += wsum[w2];
  int excl = partials[b] + woff + inc - ts;
  #pragma unroll
  for(int j=0;j<4;j++){
    int i = base+j;
    if(i < NN){ offsets[i] = excl; cursor[i] = excl; excl += c[j]; }
  }
}

__global__ void k_fill(const int* __restrict__ ei, int* __restrict__ cursor, int* __restrict__ eidx){
  int e = blockIdx.x*256 + threadIdx.x;
  if(e < NE){
    int d = ei[NE + e];
    int pos = atomicAdd(&cursor[d], 1);
    eidx[pos] = ei[e];
  }
}

// ---------------- weight transpose/convert ----------------
__global__ void k_wt(const float* __restrict__ src, unsigned short* __restrict__ dst, int K, int Ncols){
  int l = blockIdx.y;
  size_t base = (size_t)l * K * Ncols;
  int i = blockIdx.x*256 + threadIdx.x;
  if(i < K*Ncols){
    int k = i / Ncols, n = i % Ncols;
    dst[base + (size_t)n*K + k] = f2bf(src[base + i]);
  }
}

// ---------------- pipelined GEMM: C[M,256](bf16) = act(A)[M,256] @ Bt^T + bias ----------------
// Block 64m x 256n, 4 waves x (64x64). K=256, 8 slabs of 32, double-buffered DMA staging.
// TRANS: apply relu(preS*a+preT) to A fragments in registers (scale/shift LDS-cached).
template<int TRANS, bool RELUOUT, bool STATS>
__global__ __launch_bounds__(256, 3) void k_gemmp(
    const unsigned short* __restrict__ A, const unsigned short* __restrict__ Bt,
    const float* __restrict__ bias, const float* __restrict__ preS,
    const float* __restrict__ preT, unsigned short* __restrict__ C,
    float* __restrict__ stats)
{
  // per buffer: As 64 rows x 32 shorts (2048) + Bs 256 x 32 (8192) = 10240 shorts
  __shared__ __align__(16) unsigned short Sm[2][10240];   // 40 KB
  __shared__ __align__(16) float SP[2][HD];               // 2 KB scale/shift
  const int m0 = blockIdx.x*64;
  const int t = threadIdx.x;
  const int lane = t & 63, w = t >> 6;
  const int q = lane >> 4, ln = lane & 15;
  const int hs = (ln >> 1) & 3;
  const int srow = lane >> 2;
  const int cc = (lane & 3) ^ ((lane >> 3) & 3);

  f4 acc[4][4];
  #pragma unroll
  for(int i=0;i<4;i++)
    #pragma unroll
    for(int j=0;j<4;j++) acc[i][j] = (f4){0.f,0.f,0.f,0.f};

  auto issue = [&](int s, int b){
    unsigned short* As = &Sm[b][0];
    unsigned short* Bs = &Sm[b][2048];
    const int kk = s*32;
    gload16(&A[(size_t)(m0 + w*16 + srow)*HD + kk + cc*8], &As[w*512]);
    #pragma unroll
    for(int j=0;j<4;j++)
      gload16(&Bt[(size_t)(w*64 + j*16 + srow)*HD + kk + cc*8], &Bs[w*2048 + j*512]);
  };

  if(TRANS){ SP[0][t] = preS[t]; SP[1][t] = preT[t]; }
  issue(0, 0);
  issue(1, 1);
  WAITVM5L0();   // slab0 DMA done + SP writes done
  BARRIER();

  #pragma unroll
  for(int s=0; s<8; s++){
    const int b = s & 1;
    const unsigned short* As = &Sm[b][0];
    const unsigned short* Bs = &Sm[b][2048];
    bf8 af[4], bb[4];
    #pragma unroll
    for(int mi=0;mi<4;mi++) af[mi] = *(const bf8*)&As[(mi*16 + ln)*32 + (q ^ hs)*8];
    #pragma unroll
    for(int ni=0;ni<4;ni++) bb[ni] = *(const bf8*)&Bs[(w*64 + ni*16 + ln)*32 + (q ^ hs)*8];
    if(TRANS){
      f4 s0 = *(const f4*)&SP[0][s*32 + q*8];
      f4 s1 = *(const f4*)&SP[0][s*32 + q*8 + 4];
      f4 t0 = *(const f4*)&SP[1][s*32 + q*8];
      f4 t1 = *(const f4*)&SP[1][s*32 + q*8 + 4];
      float scv[8] = {s0.x,s0.y,s0.z,s0.w,s1.x,s1.y,s1.z,s1.w};
      float shv[8] = {t0.x,t0.y,t0.z,t0.w,t1.x,t1.y,t1.z,t1.w};
      #pragma unroll
      for(int mi=0;mi<4;mi++){
        #pragma unroll
        for(int j=0;j<8;j++){
          float v = bf2f((unsigned short)af[mi][j]);
          v = fmaxf(fmaf(scv[j], v, shv[j]), 0.f);
          af[mi][j] = (short)f2bf(v);
        }
      }
    }
    WAITLGKM();          // all LDS reads of buf b complete
    BARRIER();           // every wave done with buf b -> safe to overwrite
    if(s + 2 < 8) issue(s + 2, b);
    #pragma unroll
    for(int mi=0;mi<4;mi++)
      #pragma unroll
      for(int ni=0;ni<4;ni++)
        acc[mi][ni] = __builtin_amdgcn_mfma_f32_16x16x32_bf16(af[mi], bb[ni], acc[mi][ni], 0, 0, 0);
    if(s + 1 < 8){
      if(s + 2 < 8) WAITVM5();   // slab s+1 landed; slab s+2's 5 loads stay in flight
      else          WAITVM0();
      BARRIER();
    }
  }

  // ---- stats (pre-BN column sum / sumsq over valid rows) ----
  if(STATS){
    #pragma unroll
    for(int ni=0;ni<4;ni++){
      int gn = w*64 + ni*16 + ln;
      float b = bias[gn];
      float s = 0.f, ss = 0.f;
      #pragma unroll
      for(int mi=0;mi<4;mi++){
        #pragma unroll
        for(int r=0;r<4;r++){
          int gm = m0 + mi*16 + q*4 + r;
          if(gm < NN){
            float v = acc[mi][ni][r] + b;
            s += v; ss = fmaf(v, v, ss);
          }
        }
      }
      s  += __shfl_xor(s, 16, 64);  s  += __shfl_xor(s, 32, 64);
      ss += __shfl_xor(ss, 16, 64); ss += __shfl_xor(ss, 32, 64);
      if(q == 0){
        atomicAdd(&stats[gn], s);
        atomicAdd(&stats[HD + gn], ss);
      }
    }
  }

  // ---- coalesced store via per-wave LDS scratch (reuses K-loop buffers) ----
  __syncthreads();
  unsigned short* wsc = &Sm[0][0] + w*1152;   // 16 rows x 72
  #pragma unroll
  for(int mi=0;mi<4;mi++){
    #pragma unroll
    for(int ni=0;ni<4;ni++){
      float b = bias[w*64 + ni*16 + ln];
      #pragma unroll
      for(int r=0;r<4;r++){
        float v = acc[mi][ni][r] + b;
        if(RELUOUT) v = fmaxf(v, 0.f);
        wsc[(q*4 + r)*72 + ni*16 + ln] = f2bf(v);
      }
    }
    int lrow = lane >> 2;
    int gm = m0 + mi*16 + lrow;
    int ch = lane & 3;
    if(gm < NN){
      uint4 u0 = *(const uint4*)&wsc[lrow*72 + ch*8];
      uint4 u1 = *(const uint4*)&wsc[lrow*72 + (ch+4)*8];
      *(uint4*)&C[(size_t)gm*HD + w*64 + ch*8]     = u0;
      *(uint4*)&C[(size_t)gm*HD + w*64 + (ch+4)*8] = u1;
    }
  }
}

// ---------------- input projection GEMM (f32 A, K=128), single-buffered ----------------
__global__ __launch_bounds__(256, 2) void k_gemm_in(
    const float* __restrict__ A, const unsigned short* __restrict__ Bt,
    const float* __restrict__ bias, unsigned short* __restrict__ C)
{
  const int K = FINDIM;
  __shared__ __align__(16) unsigned short As[64*32];
  __shared__ __align__(16) unsigned short Bs[256*32];
  __shared__ __align__(16) unsigned short Cs[4*16*72];
  const int m0 = blockIdx.x*64;
  const int t = threadIdx.x;
  const int lane = t & 63, w = t >> 6;
  const int q = lane >> 4, ln = lane & 15;
  const int hs = (ln >> 1) & 3;
  const int srow = lane >> 2;
  const int cc = (lane & 3) ^ ((lane >> 3) & 3);
  const int mr = t >> 2;
  const int mc = (t & 3) ^ ((t >> 3) & 3);

  f4 acc[4][4];
  #pragma unroll
  for(int i=0;i<4;i++)
    #pragma unroll
    for(int j=0;j<4;j++) acc[i][j] = (f4){0.f,0.f,0.f,0.f};

  for(int kk=0; kk<K; kk+=32){
    int gm = m0 + mr;
    f4 v0 = (f4){0.f,0.f,0.f,0.f}, v1 = (f4){0.f,0.f,0.f,0.f};
    if(gm < NN){
      v0 = *(const f4*)&A[(size_t)gm*K + kk + mc*8];
      v1 = *(const f4*)&A[(size_t)gm*K + kk + mc*8 + 4];
    }
    ushort4 a0, a1;
    a0.x = f2bf(v0.x); a0.y = f2bf(v0.y); a0.z = f2bf(v0.z); a0.w = f2bf(v0.w);
    a1.x = f2bf(v1.x); a1.y = f2bf(v1.y); a1.z = f2bf(v1.z); a1.w = f2bf(v1.w);
    *(ushort4*)&As[t*8]     = a0;
    *(ushort4*)&As[t*8 + 4] = a1;
    #pragma unroll
    for(int j=0;j<4;j++)
      gload16(&Bt[(size_t)(w*64 + j*16 + srow)*K + kk + cc*8], &Bs[w*2048 + j*512]);
    __syncthreads();

    bf8 af[4], bb[4];
    #pragma unroll
    for(int mi=0;mi<4;mi++) af[mi] = *(const bf8*)&As[(mi*16 + ln)*32 + (q ^ hs)*8];
    #pragma unroll
    for(int ni=0;ni<4;ni++) bb[ni] = *(const bf8*)&Bs[(w*64 + ni*16 + ln)*32 + (q ^ hs)*8];
    #pragma unroll
    for(int mi=0;mi<4;mi++)
      #pragma unroll
      for(int ni=0;ni<4;ni++)
        acc[mi][ni] = __builtin_amdgcn_mfma_f32_16x16x32_bf16(af[mi], bb[ni], acc[mi][ni], 0, 0, 0);
    __syncthreads();
  }

  unsigned short* wsc = &Cs[w*1152];
  #pragma unroll
  for(int mi=0;mi<4;mi++){
    #pragma unroll
    for(int ni=0;ni<4;ni++){
      float b = bias[w*64 + ni*16 + ln];
      #pragma unroll
      for(int r=0;r<4;r++){
        float v = fmaxf(acc[mi][ni][r] + b, 0.f);
        wsc[(q*4 + r)*72 + ni*16 + ln] = f2bf(v);
      }
    }
    int lrow = lane >> 2;
    int gm = m0 + mi*16 + lrow;
    int ch = lane & 3;
    if(gm < NN){
      uint4 u0 = *(const uint4*)&wsc[lrow*72 + ch*8];
      uint4 u1 = *(const uint4*)&wsc[lrow*72 + (ch+4)*8];
      *(uint4*)&C[(size_t)gm*HD + w*64 + ch*8]     = u0;
      *(uint4*)&C[(size_t)gm*HD + w*64 + (ch+4)*8] = u1;
    }
  }
}

// ---------------- BN finalize ----------------
__global__ void k_bnfin(const float* __restrict__ cs, const float* __restrict__ g,
                        const float* __restrict__ be, float* __restrict__ sc, float* __restrict__ sh){
  int c = threadIdx.x;
  float mean = cs[c] * (1.0f/NN);
  float var  = cs[HD + c] * (1.0f/NN) - mean*mean;
  float s = g[c] * rsqrtf(var + 1e-5f);
  sc[c] = s;
  sh[c] = be[c] - mean*s;
}

// ---------------- aggregation ----------------
__device__ __forceinline__ f4 act4(ushort4 uv, f4 s4, f4 t4, int ident){
  f4 u;
  u.x = bf2f(uv.x); u.y = bf2f(uv.y); u.z = bf2f(uv.z); u.w = bf2f(uv.w);
  if(!ident){
    u.x = fmaxf(fmaf(s4.x, u.x, t4.x), 0.f);
    u.y = fmaxf(fmaf(s4.y, u.y, t4.y), 0.f);
    u.z = fmaxf(fmaf(s4.z, u.z, t4.z), 0.f);
    u.w = fmaxf(fmaf(s4.w, u.w, t4.w), 0.f);
  }
  return u;
}

__global__ __launch_bounds__(256) void k_agg(const unsigned short* __restrict__ src,
    unsigned short* __restrict__ dst,
    const int* __restrict__ offs, const int* __restrict__ eidx,
    const float* __restrict__ eps, int l,
    const float* __restrict__ sc, const float* __restrict__ sh, int ident)
{
  int wv = threadIdx.x >> 6;
  int n = blockIdx.x*4 + wv;
  if(n >= NN) return;
  int lane = threadIdx.x & 63;
  int c = lane << 2;
  f4 s4 = (f4){0.f,0.f,0.f,0.f}, t4 = (f4){0.f,0.f,0.f,0.f};
  if(!ident){ s4 = *(const f4*)(sc + c); t4 = *(const f4*)(sh + c); }
  float ep = 1.f + eps[l];
  f4 a = act4(*(const ushort4*)(src + (size_t)n*HD + c), s4, t4, ident);
  f4 acc;
  acc.x = ep*a.x; acc.y = ep*a.y; acc.z = ep*a.z; acc.w = ep*a.w;
  int lo = offs[n], hi = offs[n+1];
  for(int base = lo; base < hi; base += 64){
    int rem = hi - base; if(rem > 64) rem = 64;
    int idx = 0;
    if(base + lane < hi) idx = eidx[base + lane];
    int j = 0;
    for(; j + 4 <= rem; j += 4){
      int s0 = __shfl(idx, j, 64),   s1 = __shfl(idx, j+1, 64);
      int s2 = __shfl(idx, j+2, 64), s3 = __shfl(idx, j+3, 64);
      ushort4 u0 = *(const ushort4*)(src + (size_t)s0*HD + c);
      ushort4 u1 = *(const ushort4*)(src + (size_t)s1*HD + c);
      ushort4 u2 = *(const ushort4*)(src + (size_t)s2*HD + c);
      ushort4 u3 = *(const ushort4*)(src + (size_t)s3*HD + c);
      f4 a0 = act4(u0, s4, t4, ident), a1 = act4(u1, s4, t4, ident);
      f4 a2 = act4(u2, s4, t4, ident), a3 = act4(u3, s4, t4, ident);
      acc.x += (a0.x + a1.x) + (a2.x + a3.x);
      acc.y += (a0.y + a1.y) + (a2.y + a3.y);
      acc.z += (a0.z + a1.z) + (a2.z + a3.z);
      acc.w += (a0.w + a1.w) + (a2.w + a3.w);
    }
    for(; j < rem; j++){
      int s0 = __shfl(idx, j, 64);
      f4 a0 = act4(*(const ushort4*)(src + (size_t)s0*HD + c), s4, t4, ident);
      acc.x += a0.x; acc.y += a0.y; acc.z += a0.z; acc.w += a0.w;
    }
  }
  ushort4 o;
  o.x = f2bf(acc.x); o.y = f2bf(acc.y); o.z = f2bf(acc.z); o.w = f2bf(acc.w);
  *(ushort4*)(dst + (size_t)n*HD + c) = o;
}

// ---------------- pooling ----------------
__device__ __forceinline__ int lowb(const int* __restrict__ arr, int n, int key){
  int lo = 0, hi = n;
  while(lo < hi){ int mid = (lo + hi) >> 1; if(arr[mid] < key) lo = mid + 1; else hi = mid; }
  return lo;
}

__global__ __launch_bounds__(256) void k_pool(const unsigned short* __restrict__ src,
    const int* __restrict__ batch,
    const float* __restrict__ sc, const float* __restrict__ sh, float* __restrict__ pooled)
{
  int wv = threadIdx.x >> 6;
  int g = blockIdx.x*4 + wv;
  if(g >= NG) return;
  int lane = threadIdx.x & 63;
  int c = lane << 2;
  int lo = lowb(batch, NN, g);
  int hi = lowb(batch, NN, g+1);
  f4 s4 = *(const f4*)(sc + c);
  f4 t4 = *(const f4*)(sh + c);
  f4 acc = (f4){0.f,0.f,0.f,0.f};
  for(int n=lo; n<hi; n++){
    ushort4 uv = *(const ushort4*)(src + (size_t)n*HD + c);
    acc.x += fmaxf(fmaf(s4.x, bf2f(uv.x), t4.x), 0.f);
    acc.y += fmaxf(fmaf(s4.y, bf2f(uv.y), t4.y), 0.f);
    acc.z += fmaxf(fmaf(s4.z, bf2f(uv.z), t4.z), 0.f);
    acc.w += fmaxf(fmaf(s4.w, bf2f(uv.w), t4.w), 0.f);
  }
  float inv = 1.0f / fmaxf((float)(hi - lo), 1.0f);
  acc.x *= inv; acc.y *= inv; acc.z *= inv; acc.w *= inv;
  *(f4*)(pooled + (size_t)g*HD + c) = acc;
}

// ---------------- head ----------------
__global__ __launch_bounds__(128) void k_head(const float* __restrict__ pooled,
    const float* __restrict__ W1, const float* __restrict__ b1,
    const float* __restrict__ W2, const float* __restrict__ b2, float* __restrict__ out)
{
  __shared__ float p[HD];
  __shared__ float red[2];
  int g = blockIdx.x, t = threadIdx.x;
  if(t < 64) *(f4*)&p[t*4] = *(const f4*)(pooled + (size_t)g*HD + t*4);
  __syncthreads();
  float s = b1[t];
  for(int k=0;k<HD;k++) s = fmaf(p[k], W1[k*128 + t], s);
  float o = fmaxf(s, 0.f) * W2[t];
  #pragma unroll
  for(int d=1; d<64; d<<=1) o += __shfl_xor(o, d, 64);
  if((t & 63) == 0) red[t>>6] = o;
  __syncthreads();
  if(t == 0) out[g] = red[0] + red[1] + b2[0];
}

// ---------------- launch ----------------
extern "C" void kernel_launch(void* const* d_in, const int* in_sizes, int n_in,
                              void* d_out, int out_size, void* d_ws, size_t ws_size,
                              hipStream_t stream) {
  const float* x    = (const float*)d_in[0];
  const int*   ei   = (const int*)  d_in[1];
  const int*   bat  = (const int*)  d_in[2];
  const float* inW  = (const float*)d_in[3];
  const float* inb  = (const float*)d_in[4];
  const float* W1   = (const float*)d_in[5];
  const float* b1   = (const float*)d_in[6];
  const float* g1   = (const float*)d_in[7];
  const float* be1  = (const float*)d_in[8];
  const float* W2   = (const float*)d_in[9];
  const float* b2   = (const float*)d_in[10];
  const float* g2   = (const float*)d_in[11];
  const float* be2  = (const float*)d_in[12];
  const float* eps  = (const float*)d_in[13];
  const float* hW1  = (const float*)d_in[14];
  const float* hb1  = (const float*)d_in[15];
  const float* hW2  = (const float*)d_in[16];
  const float* hb2  = (const float*)d_in[17];
  float* out = (float*)d_out;

  char* p = (char*)d_ws;
  auto alloc = [&](size_t bytes)->char*{
    char* r = p; p += (bytes + 255) & ~(size_t)255; return r;
  };
  unsigned short* B0 = (unsigned short*)alloc((size_t)MPAD*HD*2);
  unsigned short* B1 = (unsigned short*)alloc((size_t)MPAD*HD*2);
  unsigned short* Wtin = (unsigned short*)alloc((size_t)FINDIM*HD*2);
  unsigned short* Wt1  = (unsigned short*)alloc((size_t)NLAYER*HD*HD*2);
  unsigned short* Wt2  = (unsigned short*)alloc((size_t)NLAYER*HD*HD*2);
  int* counts  = (int*)alloc((size_t)NN*4);
  int* offsets = (int*)alloc((size_t)(NN+1)*4);
  int* cursor  = (int*)alloc((size_t)NN*4);
  int* eidx    = (int*)alloc((size_t)NE*4);
  int* partials= (int*)alloc(128*4);
  float* cs    = (float*)alloc(4*HD*4);
  float* bnp   = (float*)alloc(4*HD*4);
  float* pooled= (float*)alloc((size_t)NG*HD*4);

  // CSR build
  k_zero<<<(NN+255)/256, 256, 0, stream>>>(counts, NN);
  k_count<<<(NE+255)/256, 256, 0, stream>>>(ei, counts);
  int nb = (NN + 1023)/1024;
  k_scan_partial<<<nb, 256, 0, stream>>>(counts, partials);
  k_scan_tot<<<1, 128, 0, stream>>>(partials, offsets, nb);
  k_scan_final<<<nb, 256, 0, stream>>>(counts, partials, offsets, cursor);
  k_fill<<<(NE+255)/256, 256, 0, stream>>>(ei, cursor, eidx);

  // weights -> bf16 [n][k]
  k_wt<<<dim3((FINDIM*HD+255)/256, 1), 256, 0, stream>>>(inW, Wtin, FINDIM, HD);
  k_wt<<<dim3((HD*HD+255)/256, NLAYER), 256, 0, stream>>>(W1, Wt1, HD, HD);
  k_wt<<<dim3((HD*HD+255)/256, NLAYER), 256, 0, stream>>>(W2, Wt2, HD, HD);

  const int MB = MPAD/64;  // 1563 m-blocks
  k_gemm_in<<<MB, 256, 0, stream>>>(x, Wtin, inb, B0);

  float* sc1 = bnp, *sh1 = bnp + HD, *sc2 = bnp + 2*HD, *sh2 = bnp + 3*HD;
  unsigned short* hbuf = B0;
  unsigned short* tbuf = B1;
  for(int l=0; l<NLAYER; l++){
    k_zero<<<4, 256, 0, stream>>>((int*)cs, 4*HD);
    k_agg<<<(NN+3)/4, 256, 0, stream>>>(hbuf, tbuf, offsets, eidx, eps, l, sc2, sh2, l==0 ? 1 : 0);
    k_gemmp<0, false, true><<<MB, 256, 0, stream>>>(tbuf, Wt1 + (size_t)l*HD*HD, b1 + l*HD,
                                                    nullptr, nullptr, hbuf, cs);
    k_bnfin<<<1, HD, 0, stream>>>(cs, g1 + l*HD, be1 + l*HD, sc1, sh1);
    k_gemmp<1, false, true><<<MB, 256, 0, stream>>>(hbuf, Wt2 + (size_t)l*HD*HD, b2 + l*HD,
                                                    sc1, sh1, tbuf, cs + 2*HD);
    k_bnfin<<<1, HD, 0, stream>>>(cs + 2*HD, g2 + l*HD, be2 + l*HD, sc2, sh2);
    unsigned short* tmp = hbuf; hbuf = tbuf; tbuf = tmp;
  }

  k_pool<<<(NG+3)/4, 256, 0, stream>>>(hbuf, bat, sc2, sh2, pooled);
  k_head<<<NG, 128, 0, stream>>>(pooled, hW1, hb1, hW2, hb2, out);
}